// Round 5
// baseline (308.987 us; speedup 1.0000x reference)
//
#include <hip/hip_runtime.h>
#include <math.h>

#define BB 32
#define SS 2048
#define EE 6144
#define KS1 16   // K-split gemm1 (K=2048, KC=128)
#define KS2 48   // K-split gemm2 (K=6144, KC=128)

typedef __bf16 bf16x8 __attribute__((ext_vector_type(8)));
typedef float f32x16 __attribute__((ext_vector_type(16)));

// ---------------- stats of original x (ddof=1) + copy to xbuf ----------------
__global__ __launch_bounds__(256) void k_stats0(const float* __restrict__ x,
                                                float* __restrict__ xbuf,
                                                float* __restrict__ stats) {
  int b = blockIdx.x;
  const float* row = x + b * SS;
  float s = 0.f, s2 = 0.f;
  for (int j = threadIdx.x; j < SS; j += 256) {
    float v = row[j];
    xbuf[b * SS + j] = v;
    s += v; s2 += v * v;
  }
  __shared__ float sm[8];
  for (int off = 32; off; off >>= 1) { s += __shfl_down(s, off); s2 += __shfl_down(s2, off); }
  int lane = threadIdx.x & 63, wid = threadIdx.x >> 6;
  if (lane == 0) { sm[wid] = s; sm[4 + wid] = s2; }
  __syncthreads();
  if (threadIdx.x == 0) {
    float ts = sm[0] + sm[1] + sm[2] + sm[3];
    float ts2 = sm[4] + sm[5] + sm[6] + sm[7];
    float mu = ts / SS;
    float var = (ts2 - SS * mu * mu) / (SS - 1);
    stats[b] = mu;
    stats[BB + b] = var;
  }
}

// ---------------- LayerNorm for attention (row layout out) ----------------
__global__ __launch_bounds__(256) void k_layernorm(const float* __restrict__ x,
                                                   const float* __restrict__ g,
                                                   const float* __restrict__ be,
                                                   float* __restrict__ u) {
  int b = blockIdx.x;
  const float* row = x + b * SS;
  float s = 0.f, s2 = 0.f;
  for (int j = threadIdx.x; j < SS; j += 256) { float v = row[j]; s += v; s2 += v * v; }
  __shared__ float sm[8];
  __shared__ float smu, srs;
  for (int off = 32; off; off >>= 1) { s += __shfl_down(s, off); s2 += __shfl_down(s2, off); }
  int lane = threadIdx.x & 63, wid = threadIdx.x >> 6;
  if (lane == 0) { sm[wid] = s; sm[4 + wid] = s2; }
  __syncthreads();
  if (threadIdx.x == 0) {
    float ts = sm[0] + sm[1] + sm[2] + sm[3];
    float ts2 = sm[4] + sm[5] + sm[6] + sm[7];
    float mu = ts / SS;
    float var = ts2 / SS - mu * mu;
    smu = mu;
    srs = rsqrtf(var + 1e-5f);
  }
  __syncthreads();
  float mu = smu, rs = srs;
  for (int j = threadIdx.x; j < SS; j += 256) {
    float v = row[j];
    u[b * SS + j] = (v - mu) * rs * g[j] + be[j];
  }
}

// ---------------- LayerNorm -> bf16 B-fragment layout Ubf[k/8][32][8] ----------------
// element U[k][b] stored at ubf[(k>>3)*256 + b*8 + (k&7)]
__global__ __launch_bounds__(256) void k_ln_bf(const float* __restrict__ x,
                                               const float* __restrict__ g,
                                               const float* __restrict__ be,
                                               __bf16* __restrict__ ubf) {
  int b = blockIdx.x;
  const float* row = x + b * SS;
  float s = 0.f, s2 = 0.f;
  for (int j = threadIdx.x; j < SS; j += 256) { float v = row[j]; s += v; s2 += v * v; }
  __shared__ float sm[8];
  __shared__ float smu, srs;
  for (int off = 32; off; off >>= 1) { s += __shfl_down(s, off); s2 += __shfl_down(s2, off); }
  int lane = threadIdx.x & 63, wid = threadIdx.x >> 6;
  if (lane == 0) { sm[wid] = s; sm[4 + wid] = s2; }
  __syncthreads();
  if (threadIdx.x == 0) {
    float ts = sm[0] + sm[1] + sm[2] + sm[3];
    float ts2 = sm[4] + sm[5] + sm[6] + sm[7];
    float mu = ts / SS;
    float var = ts2 / SS - mu * mu;
    smu = mu;
    srs = rsqrtf(var + 1e-5f);
  }
  __syncthreads();
  float mu = smu, rs = srs;
  int t = threadIdx.x;  // chunk c = t, k = 8t..8t+7  (SS/8 == 256)
  float4 v0 = *reinterpret_cast<const float4*>(row + t * 8);
  float4 v1 = *reinterpret_cast<const float4*>(row + t * 8 + 4);
  float4 g0 = *reinterpret_cast<const float4*>(g + t * 8);
  float4 g1 = *reinterpret_cast<const float4*>(g + t * 8 + 4);
  float4 b0 = *reinterpret_cast<const float4*>(be + t * 8);
  float4 b1 = *reinterpret_cast<const float4*>(be + t * 8 + 4);
  bf16x8 o;
  o[0] = (__bf16)((v0.x - mu) * rs * g0.x + b0.x);
  o[1] = (__bf16)((v0.y - mu) * rs * g0.y + b0.y);
  o[2] = (__bf16)((v0.z - mu) * rs * g0.z + b0.z);
  o[3] = (__bf16)((v0.w - mu) * rs * g0.w + b0.w);
  o[4] = (__bf16)((v1.x - mu) * rs * g1.x + b1.x);
  o[5] = (__bf16)((v1.y - mu) * rs * g1.y + b1.y);
  o[6] = (__bf16)((v1.z - mu) * rs * g1.z + b1.z);
  o[7] = (__bf16)((v1.w - mu) * rs * g1.w + b1.w);
  *reinterpret_cast<bf16x8*>(ubf + t * 256 + b * 8) = o;
}

// ---------------- attention core (head_dim=1), j-split x4 ----------------
__global__ __launch_bounds__(256) void k_attn(const float* __restrict__ u,
                                              float* __restrict__ xbuf,
                                              const float* __restrict__ ipw,
                                              const float* __restrict__ ipb,
                                              const float* __restrict__ owp,
                                              const float* __restrict__ obp) {
  int b = blockIdx.y;
  __shared__ float2 kv[SS];
  __shared__ float red[8];
  __shared__ float skmax, skmin;
  __shared__ float ssum[3][64], tsum[3][64];
  float wq = ipw[0], wk = ipw[1], wv = ipw[2];
  float bq = ipb[0], bk = ipb[1], bv = ipb[2];
  const float* urow = u + b * SS;
  float kmax = -1e30f, kmin = 1e30f;
  for (int j = threadIdx.x; j < SS; j += 256) {
    float uu = urow[j];
    float kj = fmaf(uu, wk, bk);
    float vj = fmaf(uu, wv, bv);
    kv[j] = make_float2(kj, vj);
    kmax = fmaxf(kmax, kj);
    kmin = fminf(kmin, kj);
  }
  for (int off = 32; off; off >>= 1) {
    kmax = fmaxf(kmax, __shfl_down(kmax, off));
    kmin = fminf(kmin, __shfl_down(kmin, off));
  }
  int lane = threadIdx.x & 63, wid = threadIdx.x >> 6;
  if (lane == 0) { red[wid] = kmax; red[4 + wid] = kmin; }
  __syncthreads();
  if (threadIdx.x == 0) {
    skmax = fmaxf(fmaxf(red[0], red[1]), fmaxf(red[2], red[3]));
    skmin = fminf(fminf(red[4], red[5]), fminf(red[6], red[7]));
  }
  __syncthreads();
  kmax = skmax; kmin = skmin;
  int il = threadIdx.x & 63;
  int jq = threadIdx.x >> 6;
  int i = blockIdx.x * 64 + il;
  float q = fmaf(urow[i], wq, bq);
  float m = fmaxf(q * kmax, q * kmin);
  float s = 0.f, t = 0.f;
  int j0 = jq * 512;
#pragma unroll 4
  for (int j = j0; j < j0 + 512; j++) {
    float2 c = kv[j];
    float e = __expf(fmaf(q, c.x, -m));
    s += e;
    t = fmaf(e, c.y, t);
  }
  if (jq) { ssum[jq - 1][il] = s; tsum[jq - 1][il] = t; }
  __syncthreads();
  if (jq == 0) {
    s += ssum[0][il] + ssum[1][il] + ssum[2][il];
    t += tsum[0][il] + tsum[1][il] + tsum[2][il];
    float o = t / s;
    xbuf[b * SS + i] += fmaf(o, owp[0], obp[0]);
  }
}

// ---------------- streaming MFMA GEMM: C[e][b] = sum_k W[e][k]*U[k][b] ----------------
// W: [N][K] fp32 row-major (streamed, cast to bf16 in-register).
// Ubf: B-fragment layout [K/8][32][8] bf16.
// part: [ks][N][32] fp32 partials over K-chunks of 128.
// grid: (N/128, K/128); block 256 = 4 waves; wave w owns e-rows e0=bx*128+32w..+31.
// Lane l: A-frag row = e0+(l&31), k-offset 8*(l>>5); B-frag col=(l&31), same k.
// No LDS, no barriers: 3 coalesced/granule-efficient global loads per k16-step.
__global__ __launch_bounds__(256) void k_gemm_mfma(const __bf16* __restrict__ Ubf,
                                                   const float* __restrict__ W,
                                                   float* __restrict__ part,
                                                   int K, int N) {
  int tid = threadIdx.x;
  int w = tid >> 6, lane = tid & 63;
  int l31 = lane & 31, h = lane >> 5;
  int e0 = (blockIdx.x << 7) + (w << 5);
  int kc = blockIdx.y << 7;  // KC = 128
  const float* wp = W + (size_t)(e0 + l31) * K + kc + (h << 3);
  const __bf16* up = Ubf + (size_t)((kc >> 3) + h) * 256 + (l31 << 3);
  f32x16 acc = {0.f, 0.f, 0.f, 0.f, 0.f, 0.f, 0.f, 0.f,
                0.f, 0.f, 0.f, 0.f, 0.f, 0.f, 0.f, 0.f};
#pragma unroll
  for (int t = 0; t < 8; ++t) {
    float4 a0 = *reinterpret_cast<const float4*>(wp + (t << 4));
    float4 a1 = *reinterpret_cast<const float4*>(wp + (t << 4) + 4);
    bf16x8 bv = *reinterpret_cast<const bf16x8*>(up + (t << 9));
    bf16x8 av;
    av[0] = (__bf16)a0.x; av[1] = (__bf16)a0.y; av[2] = (__bf16)a0.z; av[3] = (__bf16)a0.w;
    av[4] = (__bf16)a1.x; av[5] = (__bf16)a1.y; av[6] = (__bf16)a1.z; av[7] = (__bf16)a1.w;
    acc = __builtin_amdgcn_mfma_f32_32x32x16_bf16(av, bv, acc, 0, 0, 0);
  }
  float* out = part + (size_t)blockIdx.y * ((size_t)N * 32);
#pragma unroll
  for (int r = 0; r < 16; ++r) {
    int e = e0 + (r & 3) + ((r >> 2) << 3) + (h << 2);
    out[(size_t)e * 32 + l31] = acc[r];
  }
}

// ---------------- reduce gemm1 partials (KS1): bias + leakyrelu -> hbf (B-frag layout) ----------------
// grid: EE/8 blocks; thread t: dk=t&7, b=t>>3; chunk c=blockIdx.x covers e=8c..8c+7.
__global__ __launch_bounds__(256) void k_reduce1(const float* __restrict__ part,
                                                 const float* __restrict__ b1,
                                                 __bf16* __restrict__ hbf) {
  int c = blockIdx.x, t = threadIdx.x;
  int dk = t & 7, b = t >> 3;
  int e = (c << 3) + dk;
  float s = 0.f;
#pragma unroll
  for (int ks = 0; ks < KS1; ks++) s += part[(size_t)ks * (EE * 32) + (size_t)e * 32 + b];
  s += b1[e];
  s = s >= 0.f ? s : 0.5f * s;
  hbf[(c << 8) + t] = (__bf16)s;  // (c*256 + b*8 + dk) == c*256 + t
}

// ---------------- reduce gemm2 partials (KS2): bias + residual -> xbuf[b][s] ----------------
// block: 64 s-cols x 32 b; LDS transpose for coalesced xbuf RMW.
__global__ __launch_bounds__(256) void k_reduce2(const float* __restrict__ part,
                                                 const float* __restrict__ b2,
                                                 float* __restrict__ xbuf) {
  __shared__ float ls[32][65];
  int s0 = blockIdx.x * 64;
  int t = threadIdx.x;
#pragma unroll
  for (int i = 0; i < 8; i++) {
    int idx = t + 256 * i;  // 0..2047: s = s0 + (idx>>5), b = idx&31
    float s = 0.f;
#pragma unroll
    for (int ks = 0; ks < KS2; ks++) s += part[(size_t)ks * (SS * 32) + (size_t)s0 * 32 + idx];
    ls[idx & 31][idx >> 5] = s;
  }
  __syncthreads();
  int r = t >> 3, sc = (t & 7) * 8;
  float* xp = xbuf + (size_t)r * SS + s0 + sc;
  const float* bp = b2 + s0 + sc;
#pragma unroll
  for (int q = 0; q < 8; q++) xp[q] += ls[r][sc + q] + bp[q];
}

// ---------------- final renorm to original mean/var ----------------
__global__ __launch_bounds__(256) void k_final(const float* __restrict__ xbuf,
                                               const float* __restrict__ stats,
                                               float* __restrict__ out) {
  int b = blockIdx.x;
  const float* row = xbuf + b * SS;
  float s = 0.f, s2 = 0.f;
  for (int j = threadIdx.x; j < SS; j += 256) { float v = row[j]; s += v; s2 += v * v; }
  __shared__ float sm[8];
  __shared__ float smu, srs;
  for (int off = 32; off; off >>= 1) { s += __shfl_down(s, off); s2 += __shfl_down(s2, off); }
  int lane = threadIdx.x & 63, wid = threadIdx.x >> 6;
  if (lane == 0) { sm[wid] = s; sm[4 + wid] = s2; }
  __syncthreads();
  if (threadIdx.x == 0) {
    float ts = sm[0] + sm[1] + sm[2] + sm[3];
    float ts2 = sm[4] + sm[5] + sm[6] + sm[7];
    float mu = ts / SS;
    float var = (ts2 - SS * mu * mu) / (SS - 1);
    smu = mu;
    srs = rsqrtf(var + 2.220446049250313e-16f);
  }
  __syncthreads();
  float mu = smu, rs = srs;
  float scale = sqrtf(stats[BB + b] + 2.220446049250313e-16f);
  float mean0 = stats[b];
  for (int j = threadIdx.x; j < SS; j += 256) {
    out[b * SS + j] = (row[j] - mu) * rs * scale + mean0;
  }
}

extern "C" void kernel_launch(void* const* d_in, const int* in_sizes, int n_in,
                              void* d_out, int out_size, void* d_ws, size_t ws_size,
                              hipStream_t stream) {
  const float* x         = (const float*)d_in[0];
  const float* attn_ln_g = (const float*)d_in[1];
  const float* attn_ln_b = (const float*)d_in[2];
  const float* ipw       = (const float*)d_in[3];
  const float* ipb       = (const float*)d_in[4];
  const float* out_w     = (const float*)d_in[5];
  const float* out_b     = (const float*)d_in[6];
  const float* mlp_ln_g  = (const float*)d_in[7];
  const float* mlp_ln_b  = (const float*)d_in[8];
  const float* W1        = (const float*)d_in[9];
  const float* b1        = (const float*)d_in[10];
  const float* W2        = (const float*)d_in[11];
  const float* b2        = (const float*)d_in[12];

  float* ws    = (float*)d_ws;
  float* xbuf  = ws;                         // 65536 f
  float* u     = xbuf + BB * SS;             // 65536 f
  __bf16* ubf  = (__bf16*)(u + BB * SS);     // 65536 bf16 (32768 f)
  __bf16* hbf  = (__bf16*)(u + BB * SS + 32768);  // 196608 bf16 (98304 f)
  float* part  = u + BB * SS + 32768 + 98304;     // 3145728 f (12.6 MB)
  float* stats = part + (size_t)KS1 * EE * 32;    // 64 f

  k_stats0<<<BB, 256, 0, stream>>>(x, xbuf, stats);

  for (int l = 0; l < 2; l++) {
    // ---- attention block ----
    k_layernorm<<<BB, 256, 0, stream>>>(xbuf, attn_ln_g + l * SS, attn_ln_b + l * SS, u);
    k_attn<<<dim3(SS / 64, BB), 256, 0, stream>>>(u, xbuf, ipw + l * 3, ipb + l * 3,
                                                  out_w + l, out_b + l);
    // ---- MLP block ----
    k_ln_bf<<<BB, 256, 0, stream>>>(xbuf, mlp_ln_g + l * SS, mlp_ln_b + l * SS, ubf);
    k_gemm_mfma<<<dim3(EE / 128, KS1), 256, 0, stream>>>(ubf, W1 + (size_t)l * EE * SS,
                                                         part, SS, EE);
    k_reduce1<<<EE / 8, 256, 0, stream>>>(part, b1 + (size_t)l * EE, hbf);
    k_gemm_mfma<<<dim3(SS / 128, KS2), 256, 0, stream>>>(hbf, W2 + (size_t)l * SS * EE,
                                                         part, EE, SS);
    k_reduce2<<<SS / 64, 256, 0, stream>>>(part, b2 + (size_t)l * SS, xbuf);
  }

  k_final<<<BB, 256, 0, stream>>>(xbuf, stats, (float*)d_out);
}

// Round 6
// 153.971 us; speedup vs baseline: 2.0068x; 2.0068x over previous
//
#include <hip/hip_runtime.h>
#include <math.h>

#define BB 32
#define SS 2048
#define EE 6144
#define KS1 16   // K-split gemm1 (K=2048, KC=128)
#define KS2 48   // K-split gemm2 (K=6144, KC=128)

typedef __bf16 bf16x8 __attribute__((ext_vector_type(8)));
typedef float f32x16 __attribute__((ext_vector_type(16)));

// ---------------- stats of original x (ddof=1) + copy to xbuf ----------------
__global__ __launch_bounds__(256) void k_stats0(const float* __restrict__ x,
                                                float* __restrict__ xbuf,
                                                float* __restrict__ stats) {
  int b = blockIdx.x;
  const float* row = x + b * SS;
  float s = 0.f, s2 = 0.f;
  for (int j = threadIdx.x; j < SS; j += 256) {
    float v = row[j];
    xbuf[b * SS + j] = v;
    s += v; s2 += v * v;
  }
  __shared__ float sm[8];
  for (int off = 32; off; off >>= 1) { s += __shfl_down(s, off); s2 += __shfl_down(s2, off); }
  int lane = threadIdx.x & 63, wid = threadIdx.x >> 6;
  if (lane == 0) { sm[wid] = s; sm[4 + wid] = s2; }
  __syncthreads();
  if (threadIdx.x == 0) {
    float ts = sm[0] + sm[1] + sm[2] + sm[3];
    float ts2 = sm[4] + sm[5] + sm[6] + sm[7];
    float mu = ts / SS;
    float var = (ts2 - SS * mu * mu) / (SS - 1);
    stats[b] = mu;
    stats[BB + b] = var;
  }
}

// ---------------- LayerNorm for attention (row layout out) ----------------
__global__ __launch_bounds__(256) void k_layernorm(const float* __restrict__ x,
                                                   const float* __restrict__ g,
                                                   const float* __restrict__ be,
                                                   float* __restrict__ u) {
  int b = blockIdx.x;
  const float* row = x + b * SS;
  float s = 0.f, s2 = 0.f;
  for (int j = threadIdx.x; j < SS; j += 256) { float v = row[j]; s += v; s2 += v * v; }
  __shared__ float sm[8];
  __shared__ float smu, srs;
  for (int off = 32; off; off >>= 1) { s += __shfl_down(s, off); s2 += __shfl_down(s2, off); }
  int lane = threadIdx.x & 63, wid = threadIdx.x >> 6;
  if (lane == 0) { sm[wid] = s; sm[4 + wid] = s2; }
  __syncthreads();
  if (threadIdx.x == 0) {
    float ts = sm[0] + sm[1] + sm[2] + sm[3];
    float ts2 = sm[4] + sm[5] + sm[6] + sm[7];
    float mu = ts / SS;
    float var = ts2 / SS - mu * mu;
    smu = mu;
    srs = rsqrtf(var + 1e-5f);
  }
  __syncthreads();
  float mu = smu, rs = srs;
  for (int j = threadIdx.x; j < SS; j += 256) {
    float v = row[j];
    u[b * SS + j] = (v - mu) * rs * g[j] + be[j];
  }
}

// ---------------- LayerNorm -> bf16 B-fragment layout Ubf[k/8][32][8] ----------------
// element U[k][b] stored at ubf[(k>>3)*256 + b*8 + (k&7)]
__global__ __launch_bounds__(256) void k_ln_bf(const float* __restrict__ x,
                                               const float* __restrict__ g,
                                               const float* __restrict__ be,
                                               __bf16* __restrict__ ubf) {
  int b = blockIdx.x;
  const float* row = x + b * SS;
  float s = 0.f, s2 = 0.f;
  for (int j = threadIdx.x; j < SS; j += 256) { float v = row[j]; s += v; s2 += v * v; }
  __shared__ float sm[8];
  __shared__ float smu, srs;
  for (int off = 32; off; off >>= 1) { s += __shfl_down(s, off); s2 += __shfl_down(s2, off); }
  int lane = threadIdx.x & 63, wid = threadIdx.x >> 6;
  if (lane == 0) { sm[wid] = s; sm[4 + wid] = s2; }
  __syncthreads();
  if (threadIdx.x == 0) {
    float ts = sm[0] + sm[1] + sm[2] + sm[3];
    float ts2 = sm[4] + sm[5] + sm[6] + sm[7];
    float mu = ts / SS;
    float var = ts2 / SS - mu * mu;
    smu = mu;
    srs = rsqrtf(var + 1e-5f);
  }
  __syncthreads();
  float mu = smu, rs = srs;
  int t = threadIdx.x;  // chunk c = t, k = 8t..8t+7  (SS/8 == 256)
  float4 v0 = *reinterpret_cast<const float4*>(row + t * 8);
  float4 v1 = *reinterpret_cast<const float4*>(row + t * 8 + 4);
  float4 g0 = *reinterpret_cast<const float4*>(g + t * 8);
  float4 g1 = *reinterpret_cast<const float4*>(g + t * 8 + 4);
  float4 b0 = *reinterpret_cast<const float4*>(be + t * 8);
  float4 b1 = *reinterpret_cast<const float4*>(be + t * 8 + 4);
  bf16x8 o;
  o[0] = (__bf16)((v0.x - mu) * rs * g0.x + b0.x);
  o[1] = (__bf16)((v0.y - mu) * rs * g0.y + b0.y);
  o[2] = (__bf16)((v0.z - mu) * rs * g0.z + b0.z);
  o[3] = (__bf16)((v0.w - mu) * rs * g0.w + b0.w);
  o[4] = (__bf16)((v1.x - mu) * rs * g1.x + b1.x);
  o[5] = (__bf16)((v1.y - mu) * rs * g1.y + b1.y);
  o[6] = (__bf16)((v1.z - mu) * rs * g1.z + b1.z);
  o[7] = (__bf16)((v1.w - mu) * rs * g1.w + b1.w);
  *reinterpret_cast<bf16x8*>(ubf + t * 256 + b * 8) = o;
}

// ---------------- attention core (head_dim=1), j-split x4 ----------------
__global__ __launch_bounds__(256) void k_attn(const float* __restrict__ u,
                                              float* __restrict__ xbuf,
                                              const float* __restrict__ ipw,
                                              const float* __restrict__ ipb,
                                              const float* __restrict__ owp,
                                              const float* __restrict__ obp) {
  int b = blockIdx.y;
  __shared__ float2 kv[SS];
  __shared__ float red[8];
  __shared__ float skmax, skmin;
  __shared__ float ssum[3][64], tsum[3][64];
  float wq = ipw[0], wk = ipw[1], wv = ipw[2];
  float bq = ipb[0], bk = ipb[1], bv = ipb[2];
  const float* urow = u + b * SS;
  float kmax = -1e30f, kmin = 1e30f;
  for (int j = threadIdx.x; j < SS; j += 256) {
    float uu = urow[j];
    float kj = fmaf(uu, wk, bk);
    float vj = fmaf(uu, wv, bv);
    kv[j] = make_float2(kj, vj);
    kmax = fmaxf(kmax, kj);
    kmin = fminf(kmin, kj);
  }
  for (int off = 32; off; off >>= 1) {
    kmax = fmaxf(kmax, __shfl_down(kmax, off));
    kmin = fminf(kmin, __shfl_down(kmin, off));
  }
  int lane = threadIdx.x & 63, wid = threadIdx.x >> 6;
  if (lane == 0) { red[wid] = kmax; red[4 + wid] = kmin; }
  __syncthreads();
  if (threadIdx.x == 0) {
    skmax = fmaxf(fmaxf(red[0], red[1]), fmaxf(red[2], red[3]));
    skmin = fminf(fminf(red[4], red[5]), fminf(red[6], red[7]));
  }
  __syncthreads();
  kmax = skmax; kmin = skmin;
  int il = threadIdx.x & 63;
  int jq = threadIdx.x >> 6;
  int i = blockIdx.x * 64 + il;
  float q = fmaf(urow[i], wq, bq);
  float m = fmaxf(q * kmax, q * kmin);
  float s = 0.f, t = 0.f;
  int j0 = jq * 512;
#pragma unroll 4
  for (int j = j0; j < j0 + 512; j++) {
    float2 c = kv[j];
    float e = __expf(fmaf(q, c.x, -m));
    s += e;
    t = fmaf(e, c.y, t);
  }
  if (jq) { ssum[jq - 1][il] = s; tsum[jq - 1][il] = t; }
  __syncthreads();
  if (jq == 0) {
    s += ssum[0][il] + ssum[1][il] + ssum[2][il];
    t += tsum[0][il] + tsum[1][il] + tsum[2][il];
    float o = t / s;
    xbuf[b * SS + i] += fmaf(o, owp[0], obp[0]);
  }
}

// ---------------- streaming MFMA GEMM: C[e][b] = sum_k W[e][k]*U[k][b] ----------------
// W: [N][K] fp32 row-major (streamed, cast to bf16 in-register).
// Ubf: B-fragment layout [K/8][32][8] bf16.
// part: [ks][N][32] fp32 partials over K-chunks of 128.
// grid: (N/128, K/128); block 256 = 4 waves; wave w owns e-rows e0=bx*128+32w..+31.
__global__ __launch_bounds__(256) void k_gemm_mfma(const __bf16* __restrict__ Ubf,
                                                   const float* __restrict__ W,
                                                   float* __restrict__ part,
                                                   int K, int N) {
  int tid = threadIdx.x;
  int w = tid >> 6, lane = tid & 63;
  int l31 = lane & 31, h = lane >> 5;
  int e0 = (blockIdx.x << 7) + (w << 5);
  int kc = blockIdx.y << 7;  // KC = 128
  const float* wp = W + (size_t)(e0 + l31) * K + kc + (h << 3);
  const __bf16* up = Ubf + (size_t)((kc >> 3) + h) * 256 + (l31 << 3);
  f32x16 acc = {0.f, 0.f, 0.f, 0.f, 0.f, 0.f, 0.f, 0.f,
                0.f, 0.f, 0.f, 0.f, 0.f, 0.f, 0.f, 0.f};
#pragma unroll
  for (int t = 0; t < 8; ++t) {
    float4 a0 = *reinterpret_cast<const float4*>(wp + (t << 4));
    float4 a1 = *reinterpret_cast<const float4*>(wp + (t << 4) + 4);
    bf16x8 bv = *reinterpret_cast<const bf16x8*>(up + (t << 9));
    bf16x8 av;
    av[0] = (__bf16)a0.x; av[1] = (__bf16)a0.y; av[2] = (__bf16)a0.z; av[3] = (__bf16)a0.w;
    av[4] = (__bf16)a1.x; av[5] = (__bf16)a1.y; av[6] = (__bf16)a1.z; av[7] = (__bf16)a1.w;
    acc = __builtin_amdgcn_mfma_f32_32x32x16_bf16(av, bv, acc, 0, 0, 0);
  }
  float* out = part + (size_t)blockIdx.y * ((size_t)N * 32);
#pragma unroll
  for (int r = 0; r < 16; ++r) {
    int e = e0 + (r & 3) + ((r >> 2) << 3) + (h << 2);
    out[(size_t)e * 32 + l31] = acc[r];
  }
}

// ---------------- reduce gemm1 partials (KS1): bias + leakyrelu -> hbf (B-frag layout) ----------------
// grid: EE/8 blocks x 256 thr; one element/thread, 8-wide load batches.
// element: e = bx*8 + (t>>5), b = t&31  (addr base+t is coalesced per slab)
__global__ __launch_bounds__(256) void k_reduce1(const float* __restrict__ part,
                                                 const float* __restrict__ b1,
                                                 __bf16* __restrict__ hbf) {
  __shared__ float ls[256];
  int t = threadIdx.x;
  int base = blockIdx.x << 8;
  float s = 0.f;
#pragma unroll
  for (int g = 0; g < KS1; g += 8) {
    float v[8];
#pragma unroll
    for (int j = 0; j < 8; j++) v[j] = part[(size_t)(g + j) * (EE * 32) + base + t];
#pragma unroll
    for (int j = 0; j < 8; j++) s += v[j];
  }
  int e = (blockIdx.x << 3) + (t >> 5);
  s += b1[e];
  s = s >= 0.f ? s : 0.5f * s;
  ls[((t & 31) << 3) | (t >> 5)] = s;  // B-frag position b*8+dk
  __syncthreads();
  hbf[base + t] = (__bf16)ls[t];
}

// ---------------- reduce gemm2 partials (KS2): bias + residual -> xbuf[b][s] ----------------
// grid: SS/8 blocks x 256 thr; one element/thread, 8-wide load batches.
// element: s = bx*8 + (t>>5), b = t&31; LDS transpose for coalesced xbuf RMW.
__global__ __launch_bounds__(256) void k_reduce2(const float* __restrict__ part,
                                                 const float* __restrict__ b2,
                                                 float* __restrict__ xbuf) {
  __shared__ float ls[32][9];
  int t = threadIdx.x;
  int base = blockIdx.x << 8;
  float s = 0.f;
#pragma unroll
  for (int g = 0; g < KS2; g += 8) {
    float v[8];
#pragma unroll
    for (int j = 0; j < 8; j++) v[j] = part[(size_t)(g + j) * (SS * 32) + base + t];
#pragma unroll
    for (int j = 0; j < 8; j++) s += v[j];
  }
  ls[t & 31][t >> 5] = s;
  __syncthreads();
  int r = t >> 3, sc = t & 7;
  int scol = (blockIdx.x << 3) + sc;
  xbuf[(size_t)r * SS + scol] += ls[r][sc] + b2[scol];
}

// ---------------- final renorm to original mean/var ----------------
__global__ __launch_bounds__(256) void k_final(const float* __restrict__ xbuf,
                                               const float* __restrict__ stats,
                                               float* __restrict__ out) {
  int b = blockIdx.x;
  const float* row = xbuf + b * SS;
  float s = 0.f, s2 = 0.f;
  for (int j = threadIdx.x; j < SS; j += 256) { float v = row[j]; s += v; s2 += v * v; }
  __shared__ float sm[8];
  __shared__ float smu, srs;
  for (int off = 32; off; off >>= 1) { s += __shfl_down(s, off); s2 += __shfl_down(s2, off); }
  int lane = threadIdx.x & 63, wid = threadIdx.x >> 6;
  if (lane == 0) { sm[wid] = s; sm[4 + wid] = s2; }
  __syncthreads();
  if (threadIdx.x == 0) {
    float ts = sm[0] + sm[1] + sm[2] + sm[3];
    float ts2 = sm[4] + sm[5] + sm[6] + sm[7];
    float mu = ts / SS;
    float var = (ts2 - SS * mu * mu) / (SS - 1);
    smu = mu;
    srs = rsqrtf(var + 2.220446049250313e-16f);
  }
  __syncthreads();
  float mu = smu, rs = srs;
  float scale = sqrtf(stats[BB + b] + 2.220446049250313e-16f);
  float mean0 = stats[b];
  for (int j = threadIdx.x; j < SS; j += 256) {
    out[b * SS + j] = (row[j] - mu) * rs * scale + mean0;
  }
}

extern "C" void kernel_launch(void* const* d_in, const int* in_sizes, int n_in,
                              void* d_out, int out_size, void* d_ws, size_t ws_size,
                              hipStream_t stream) {
  const float* x         = (const float*)d_in[0];
  const float* attn_ln_g = (const float*)d_in[1];
  const float* attn_ln_b = (const float*)d_in[2];
  const float* ipw       = (const float*)d_in[3];
  const float* ipb       = (const float*)d_in[4];
  const float* out_w     = (const float*)d_in[5];
  const float* out_b     = (const float*)d_in[6];
  const float* mlp_ln_g  = (const float*)d_in[7];
  const float* mlp_ln_b  = (const float*)d_in[8];
  const float* W1        = (const float*)d_in[9];
  const float* b1        = (const float*)d_in[10];
  const float* W2        = (const float*)d_in[11];
  const float* b2        = (const float*)d_in[12];

  float* ws    = (float*)d_ws;
  float* xbuf  = ws;                         // 65536 f
  float* u     = xbuf + BB * SS;             // 65536 f
  __bf16* ubf  = (__bf16*)(u + BB * SS);     // 65536 bf16 (32768 f)
  __bf16* hbf  = (__bf16*)(u + BB * SS + 32768);  // 196608 bf16 (98304 f)
  float* part  = u + BB * SS + 32768 + 98304;     // 3145728 f (12.6 MB)
  float* stats = part + (size_t)KS1 * EE * 32;    // 64 f

  k_stats0<<<BB, 256, 0, stream>>>(x, xbuf, stats);

  for (int l = 0; l < 2; l++) {
    // ---- attention block ----
    k_layernorm<<<BB, 256, 0, stream>>>(xbuf, attn_ln_g + l * SS, attn_ln_b + l * SS, u);
    k_attn<<<dim3(SS / 64, BB), 256, 0, stream>>>(u, xbuf, ipw + l * 3, ipb + l * 3,
                                                  out_w + l, out_b + l);
    // ---- MLP block ----
    k_ln_bf<<<BB, 256, 0, stream>>>(xbuf, mlp_ln_g + l * SS, mlp_ln_b + l * SS, ubf);
    k_gemm_mfma<<<dim3(EE / 128, KS1), 256, 0, stream>>>(ubf, W1 + (size_t)l * EE * SS,
                                                         part, SS, EE);
    k_reduce1<<<EE / 8, 256, 0, stream>>>(part, b1 + (size_t)l * EE, hbf);
    k_gemm_mfma<<<dim3(SS / 128, KS2), 256, 0, stream>>>(hbf, W2 + (size_t)l * SS * EE,
                                                         part, EE, SS);
    k_reduce2<<<SS / 8, 256, 0, stream>>>(part, b2 + (size_t)l * SS, xbuf);
  }

  k_final<<<BB, 256, 0, stream>>>(xbuf, stats, (float*)d_out);
}